// Round 1
// baseline (115.618 us; speedup 1.0000x reference)
//
#include <hip/hip_runtime.h>

#define FG 256
#define TILE 2048

// ---------------- kernel 0: zero the extraction counter ----------------
__global__ void init_kernel(int* counter) {
    if (threadIdx.x == 0) *counter = 0;
}

// ---------------- kernel 1: gather foreground logits -------------------
__global__ void extract_kernel(const float* __restrict__ logits,
                               const int* __restrict__ targets,
                               int* __restrict__ counter,
                               float* __restrict__ fgraw, int n) {
    int i = blockIdx.x * blockDim.x + threadIdx.x;
    if (i < n && targets[i] == 1) {
        int p = atomicAdd(counter, 1);        // order irrelevant; we sort next
        fgraw[p] = logits[i];
    }
}

// ------- kernel 2: bitonic-sort 256 fg logits, compute a_i, zero b ------
__global__ void sort_a_kernel(const float* __restrict__ fgraw,
                              float* __restrict__ sf,
                              float* __restrict__ a,
                              float* __restrict__ b) {
    __shared__ float s[FG];
    const int tid = threadIdx.x;
    s[tid] = fgraw[tid];
    __syncthreads();
    for (int k = 2; k <= FG; k <<= 1) {
        for (int j = k >> 1; j > 0; j >>= 1) {
            int ixj = tid ^ j;
            if (ixj > tid) {
                float x = s[tid], y = s[ixj];
                bool dir = (tid & k) == 0;     // ascending block
                if ((x > y) == dir) { s[tid] = y; s[ixj] = x; }
            }
            __syncthreads();
        }
    }
    const float fi = s[tid];
    float sum = 0.f;
    #pragma unroll 8
    for (int j = 0; j < FG; ++j) {
        float v = (s[j] - fi) * 0.5f + 0.5f;
        v = fminf(fmaxf(v, 0.f), 1.f);
        sum += v;
    }
    sf[tid] = fi;
    a[tid]  = sum + 0.5f;   // a = sum(tmp1) + 0.5
    b[tid]  = 0.f;          // zeroed before b_kernel (stream-ordered)
}

// ------- kernel 3: b_all_i = sum over ALL logits of clip((l-f_i)/2+0.5) -
// (fg contribution subtracted later: sum_fg clip == a_i - 0.5)
__global__ void __launch_bounds__(256) b_kernel(const float* __restrict__ logits,
                                                const float* __restrict__ sf,
                                                float* __restrict__ b, int n) {
    __shared__ float4 tile[TILE / 4];
    const int tid  = threadIdx.x;
    const int base = blockIdx.x * TILE;
    // cooperative load + pre-transform x = 0.5*l + 0.5 (pad -> huge negative)
    #pragma unroll
    for (int v = 0; v < TILE / 4 / 256; ++v) {
        int q = tid + v * 256;             // float4 slot within tile
        int g = base + q * 4;
        float4 x;
        if (g + 3 < n) {
            x = ((const float4*)logits)[(base >> 2) + q];
        } else {
            x.x = (g + 0 < n) ? logits[g + 0] : -1e30f;
            x.y = (g + 1 < n) ? logits[g + 1] : -1e30f;
            x.z = (g + 2 < n) ? logits[g + 2] : -1e30f;
            x.w = (g + 3 < n) ? logits[g + 3] : -1e30f;
        }
        x.x = 0.5f * x.x + 0.5f; x.y = 0.5f * x.y + 0.5f;
        x.z = 0.5f * x.z + 0.5f; x.w = 0.5f * x.w + 0.5f;
        tile[q] = x;
    }
    __syncthreads();
    const float d = 0.5f * sf[tid];        // clip((l-f)/2+0.5) == clip(x-d)
    float a0 = 0.f, a1 = 0.f, a2 = 0.f, a3 = 0.f;
    #pragma unroll 8
    for (int j = 0; j < TILE / 4; ++j) {   // LDS broadcast: all lanes same addr
        float4 x = tile[j];
        a0 += fminf(fmaxf(x.x - d, 0.f), 1.f);
        a1 += fminf(fmaxf(x.y - d, 0.f), 1.f);
        a2 += fminf(fmaxf(x.z - d, 0.f), 1.f);
        a3 += fminf(fmaxf(x.w - d, 0.f), 1.f);
    }
    atomicAdd(&b[tid], (a0 + a1) + (a2 + a3));
}

// ------- kernel 4: cur = a/(a+b_bg); prefix-max ascending; loss ---------
__global__ void final_kernel(const float* __restrict__ a,
                             const float* __restrict__ b,
                             float* __restrict__ out) {
    __shared__ float cur[FG];
    const int tid = threadIdx.x;
    float ai = a[tid];
    float bb = b[tid] - (ai - 0.5f);       // remove fg contribution -> bg only
    cur[tid] = ai / (ai + bb);
    __syncthreads();
    if (tid == 0) {
        float mp = 0.f, sum = 0.f;
        for (int i = 0; i < FG; ++i) {     // f sorted ascending -> scan order
            mp = fmaxf(mp, cur[i]);
            sum += mp;                      // prec emitted is the running max
        }
        out[0] = 1.f - sum / (float)FG;
    }
}

extern "C" void kernel_launch(void* const* d_in, const int* in_sizes, int n_in,
                              void* d_out, int out_size, void* d_ws, size_t ws_size,
                              hipStream_t stream) {
    const float* logits  = (const float*)d_in[0];
    const int*   targets = (const int*)d_in[1];
    const int n = in_sizes[0];

    float* w       = (float*)d_ws;
    int*   counter = (int*)d_ws;           // ws[0]
    float* fgraw   = w + 64;
    float* sf      = w + 64 + FG;
    float* a       = w + 64 + 2 * FG;
    float* b       = w + 64 + 3 * FG;
    float* out     = (float*)d_out;

    init_kernel<<<1, 64, 0, stream>>>(counter);
    int nb1 = (n + 255) / 256;
    extract_kernel<<<nb1, 256, 0, stream>>>(logits, targets, counter, fgraw, n);
    sort_a_kernel<<<1, FG, 0, stream>>>(fgraw, sf, a, b);
    int nb3 = (n + TILE - 1) / TILE;
    b_kernel<<<nb3, 256, 0, stream>>>(logits, sf, b, n);
    final_kernel<<<1, FG, 0, stream>>>(a, b, out);
}